// Round 7
// baseline (262.173 us; speedup 1.0000x reference)
//
#include <hip/hip_runtime.h>
#include <hip/hip_bf16.h>
#include <cstdint>
#include <cstddef>

// ThermodynamicAttention: q=xWq+bq, k=xWk+bk, v=xWv+bv (B=4,S=2048,D=1024)
// scores = q@k^T / 8 / temp; probs = softmax(scores); H = mean row entropy
// out0 = probs@v (fp32, 8388608 elems), out1 = H (1 elem)
//
// R15: counted-vmcnt 4-phase 256x256 pipeline with RACE-FREE stage placement.
// R14's failure: same-phase WAR races (stage A0 in Ph_a vs ah reads; stage B0
// in Ph_b vs bhi reads). Rule (proven by R12): a region may be staged only in
// a phase strictly AFTER its last ds_read phase (lgkm0+barrier separation).
// A halves retire at Ph_a end; B halves at Ph_b end. Hence:
//   Ph_a: read ah(t)[8]                  | lgkm0 | bar | MFMA ll | bar
//   Ph_b: read bhi(t)[4]; stage A0+A1(t+2)[4] | lgkm0 | bar | MFMA hl |
//         vmcnt(4) | bar
//   Ph_c: read blo(t+1)[4]; stage B0+B1(t+2)[4] | lgkm0 | bar | MFMA lh | bar
//   Ph_d: read af(t+1)[8]                | lgkm0 | bar | MFMA hh | bar
// vmcnt(4) at Ph_b(t): queue = A(t+1)[Ph_b(t-1)] + B(t+1)[Ph_c(t-1)] +
// A(t+2)[Ph_b(t)] = 12 -> retires exactly all 8 tile-(t+1) stages, keeps 4
// in flight (counted, never 0 = T4/m218-V0). All t+1 reads are after this
// wait + barrier (cross-wave RAW safe). No phase stages a region read in the
// same phase (WAR safe). Tail: t=NT-2 clamped stages hit dead regions only;
// t=NT-1 writes identical bytes. Phase boundaries: sched_barrier(0) +
// asm s_barrier("memory") + sched_barrier(0) (raw s_barrier is not a
// compiler fence -- R10 lesson). PV keeps the 128^2 path with folded stats.
//
// Workspace layout (bytes), ~104 MB:
//   0          qb    (bf16, 16MB)  [q pre-scaled by 1/(8*temp)]
//   16777216   kb    (bf16, 16MB)
//   33554432   vt    (bf16 v transposed [b][d][s], 16MB)
//   50331648   xb    (bf16 x, 16MB)
//   67108864   Wt    (bf16 [Wqt|Wkt|Wvt], 6MB)
//   73400320   Pt    (bf16 e^x, 4x2048x2048, 32MB)
//   106954752  stats (fp32 [8192][32][2], 2MB)
//   109084672  Hrow  (fp32 [8192], 32KB)

typedef __attribute__((ext_vector_type(8))) short short8;
typedef __attribute__((ext_vector_type(4))) short short4v;
typedef __attribute__((ext_vector_type(4))) float f32x4;

#define GLOBAL_AS __attribute__((address_space(1)))
#define LDS_AS __attribute__((address_space(3)))

#define PHASE_BARRIER()                                   \
  do {                                                    \
    __builtin_amdgcn_sched_barrier(0);                    \
    asm volatile("s_barrier" ::: "memory");               \
    __builtin_amdgcn_sched_barrier(0);                    \
  } while (0)

#define LGKM0()                                           \
  do {                                                    \
    asm volatile("s_waitcnt lgkmcnt(0)" ::: "memory");    \
    __builtin_amdgcn_sched_barrier(0);                    \
  } while (0)

__device__ __forceinline__ void async_load16(const void* g, void* lds) {
  __builtin_amdgcn_global_load_lds((GLOBAL_AS void*)g, (LDS_AS void*)lds, 16, 0, 0);
}

__device__ __forceinline__ short f2bf_s(float x) {
  __hip_bfloat16 h = __float2bfloat16(x);
  return *reinterpret_cast<short*>(&h);
}

// ===========================================================================
// 256x256 deep-pipelined GEMM body (counted-vmcnt schedule, see header).
// 512 threads = 8 waves in 2x4; per wave 128x64 output = acc[8][4] f32x4.
// LDS per operand: 2 bufs x 2 halves x (128 rows x 64 cols bf16 = 16KB).
// Half layout = proven swizzle: chunk (row r, g) at r*8 + (g ^ (r&7));
// read col-group kk*4+quad at ((kk*4+quad) ^ (rc&7)) -> 0 bank conflicts.
// MODE 1: bf16 C + bias, scaled by 1/(8*aux[0]) if aux (q) else 1 (k)
// MODE 2: bf16 transposed-v + bias   (vt[b][col][s], b=row>>11)
// MODE 3: P~ = bf16(e^acc) + per-(row,chunk64) stats (l = sum e, w = sum e*x)
// ===========================================================================
template <int MODE>
__device__ __forceinline__
void gemm256_body(const __hip_bfloat16* __restrict__ A,
                  const __hip_bfloat16* __restrict__ Bt,
                  void* __restrict__ Cout,
                  const float* __restrict__ bias,
                  int K, int lda, int ldb, int ldc,
                  __hip_bfloat16* __restrict__ sA,   // [2][2][8192] bf16
                  __hip_bfloat16* __restrict__ sB,
                  int m0, int n0,
                  const float* __restrict__ aux,
                  float* __restrict__ stats) {
  const int tid  = threadIdx.x;
  const int lane = tid & 63;
  const int wid  = tid >> 6;
  const int wm   = (wid >> 2) * 128;   // 0 / 128
  const int wn   = (wid & 3) * 64;     // 0 / 64 / 128 / 192
  const int quad = lane >> 4;
  const int rc   = lane & 15;
  const int rc7  = rc & 7;
  const int wnr  = wn & 64;            // row offset inside B half

  f32x4 acc[8][4] = {};

  const int r0   = tid >> 3;                     // 0..63
  const int scol = ((tid & 7) ^ (r0 & 7)) * 8;   // pre-swizzled source col
  const __hip_bfloat16* Ag = A  + (size_t)(m0 + r0) * lda + scol;
  const __hip_bfloat16* Bg = Bt + (size_t)(n0 + r0) * ldb + scol;

  const int NT = K >> 6;

  auto stA = [&](int buf, int half, int kofs) {
    const __hip_bfloat16* s = Ag + (size_t)(half * 128) * lda + kofs;
    __hip_bfloat16* d = sA + (size_t)buf * 16384 + (size_t)half * 8192 + tid * 8;
    async_load16(s, d);
    async_load16(s + (size_t)64 * lda, d + 4096);
  };
  auto stB = [&](int buf, int half, int kofs) {
    const __hip_bfloat16* s = Bg + (size_t)(half * 128) * ldb + kofs;
    __hip_bfloat16* d = sB + (size_t)buf * 16384 + (size_t)half * 8192 + tid * 8;
    async_load16(s, d);
    async_load16(s + (size_t)64 * ldb, d + 4096);
  };

  const __hip_bfloat16* sAh = sA + (size_t)(wm >> 7) * 8192;
  const __hip_bfloat16* sBh = sB + (size_t)(wn >> 7) * 8192;

  short8 af[2][4], ah[2][4], blo[2][2], bhi[2][2];

  // ---- prologue: stage tile0 + tile1 (16 loads); vmcnt(8) retires tile0;
  // barrier (cross-wave); pre-read af(0)+blo(0).
  {
    const int k1 = (NT > 1) ? 64 : 0;
    stA(0, 0, 0);  stA(0, 1, 0);  stB(0, 0, 0);  stB(0, 1, 0);
    stA(1, 0, k1); stA(1, 1, k1); stB(1, 0, k1); stB(1, 1, k1);
  }
  asm volatile("s_waitcnt vmcnt(8)" ::: "memory");
  PHASE_BARRIER();
#pragma unroll
  for (int kk = 0; kk < 2; ++kk) {
    const int gs = ((kk * 4 + quad) ^ rc7) * 8;
#pragma unroll
    for (int i = 0; i < 4; ++i)
      af[kk][i] = *(const short8*)&sAh[(i * 16 + rc) * 64 + gs];
#pragma unroll
    for (int j = 0; j < 2; ++j)
      blo[kk][j] = *(const short8*)&sBh[(wnr + j * 16 + rc) * 64 + gs];
  }
  LGKM0();

  for (int t = 0; t < NT; ++t) {
    const int buf = t & 1;
    const __hip_bfloat16* sAc = sAh + buf * 16384;        // tile t
    const __hip_bfloat16* sBc = sBh + buf * 16384;
    const __hip_bfloat16* sAn = sAh + (buf ^ 1) * 16384;  // tile t+1
    const __hip_bfloat16* sBn = sBh + (buf ^ 1) * 16384;
    const int k2 = ((t + 2 < NT) ? t + 2 : NT - 1) * 64;

    // ---- Ph_a: read ah(t) [8]. No stages (A halves still being read). ----
#pragma unroll
    for (int kk = 0; kk < 2; ++kk) {
      const int gs = ((kk * 4 + quad) ^ rc7) * 8;
#pragma unroll
      for (int i = 0; i < 4; ++i)
        ah[kk][i] = *(const short8*)&sAc[((i + 4) * 16 + rc) * 64 + gs];
    }
    LGKM0();
    PHASE_BARRIER();
    __builtin_amdgcn_s_setprio(1);
#pragma unroll
    for (int mi = 0; mi < 4; ++mi)
#pragma unroll
      for (int ni = 0; ni < 2; ++ni)
#pragma unroll
        for (int kk = 0; kk < 2; ++kk)
          acc[mi][ni] = __builtin_amdgcn_mfma_f32_16x16x32_bf16(
              af[kk][mi], blo[kk][ni], acc[mi][ni], 0, 0, 0);
    __builtin_amdgcn_s_setprio(0);
    PHASE_BARRIER();

    // ---- Ph_b: read bhi(t) [4]; stage A0+A1(t+2) (A retired at Ph_a end);
    //      MFMA hl; COUNTED vmcnt(4) ----
#pragma unroll
    for (int kk = 0; kk < 2; ++kk) {
      const int gs = ((kk * 4 + quad) ^ rc7) * 8;
#pragma unroll
      for (int j = 0; j < 2; ++j)
        bhi[kk][j] = *(const short8*)&sBc[(wnr + (j + 2) * 16 + rc) * 64 + gs];
    }
    stA(buf, 0, k2);
    stA(buf, 1, k2);
    LGKM0();
    PHASE_BARRIER();
    __builtin_amdgcn_s_setprio(1);
#pragma unroll
    for (int mi = 0; mi < 4; ++mi)
#pragma unroll
      for (int ni = 0; ni < 2; ++ni)
#pragma unroll
        for (int kk = 0; kk < 2; ++kk)
          acc[4 + mi][ni] = __builtin_amdgcn_mfma_f32_16x16x32_bf16(
              ah[kk][mi], blo[kk][ni], acc[4 + mi][ni], 0, 0, 0);
    __builtin_amdgcn_s_setprio(0);
    // Counted wait (T4): queue = A(t+1)[4] + B(t+1)[4] + A(t+2)[4];
    // vmcnt(4) retires exactly all 8 tile-(t+1) stages, keeps 4 in flight.
    asm volatile("s_waitcnt vmcnt(4)" ::: "memory");
    PHASE_BARRIER();

    // ---- Ph_c: read blo(t+1) [4] (safe: post vmcnt(4)+barrier);
    //      stage B0+B1(t+2) (B retired at Ph_b end); MFMA lh ----
#pragma unroll
    for (int kk = 0; kk < 2; ++kk) {
      const int gs = ((kk * 4 + quad) ^ rc7) * 8;
#pragma unroll
      for (int j = 0; j < 2; ++j)
        blo[kk][j] = *(const short8*)&sBn[(wnr + j * 16 + rc) * 64 + gs];
    }
    stB(buf, 0, k2);
    stB(buf, 1, k2);
    LGKM0();
    PHASE_BARRIER();
    __builtin_amdgcn_s_setprio(1);
#pragma unroll
    for (int mi = 0; mi < 4; ++mi)
#pragma unroll
      for (int nj = 0; nj < 2; ++nj)
#pragma unroll
        for (int kk = 0; kk < 2; ++kk)
          acc[mi][2 + nj] = __builtin_amdgcn_mfma_f32_16x16x32_bf16(
              af[kk][mi], bhi[kk][nj], acc[mi][2 + nj], 0, 0, 0);
    __builtin_amdgcn_s_setprio(0);
    PHASE_BARRIER();

    // ---- Ph_d: read af(t+1) [8]; MFMA hh ----
#pragma unroll
    for (int kk = 0; kk < 2; ++kk) {
      const int gs = ((kk * 4 + quad) ^ rc7) * 8;
#pragma unroll
      for (int i = 0; i < 4; ++i)
        af[kk][i] = *(const short8*)&sAn[(i * 16 + rc) * 64 + gs];
    }
    LGKM0();
    PHASE_BARRIER();
    __builtin_amdgcn_s_setprio(1);
#pragma unroll
    for (int mi = 0; mi < 4; ++mi)
#pragma unroll
      for (int nj = 0; nj < 2; ++nj)
#pragma unroll
        for (int kk = 0; kk < 2; ++kk)
          acc[4 + mi][2 + nj] = __builtin_amdgcn_mfma_f32_16x16x32_bf16(
              ah[kk][mi], bhi[kk][nj], acc[4 + mi][2 + nj], 0, 0, 0);
    __builtin_amdgcn_s_setprio(0);
    PHASE_BARRIER();
  }
  // drain stale tail stages so LDS writes can't land after block retire
  asm volatile("s_waitcnt vmcnt(0)" ::: "memory");

  // ---- epilogues. C/D layout (m89-verified): row = quad*4+reg, col = rc ----
  if (MODE == 3) {
    const int chunk = (n0 + wn) >> 6;
#pragma unroll
    for (int mi = 0; mi < 8; ++mi) {
      float l_acc[4] = {}, w_acc[4] = {};
#pragma unroll
      for (int ni = 0; ni < 4; ++ni)
#pragma unroll
        for (int r = 0; r < 4; ++r) {
          const float xv = acc[mi][ni][r];   // already /(8*temp): q pre-scaled
          const float e = __expf(xv);
          acc[mi][ni][r] = e;
          l_acc[r] += e;
          w_acc[r] += e * xv;
        }
#pragma unroll
      for (int r = 0; r < 4; ++r) {
        float l = l_acc[r], w = w_acc[r];
#pragma unroll
        for (int off = 1; off < 16; off <<= 1) {
          l += __shfl_xor(l, off);
          w += __shfl_xor(w, off);
        }
        if (rc == 0) {
          const int row = m0 + wm + mi * 16 + quad * 4 + r;
          *(float2*)&stats[((size_t)row * 32 + chunk) * 2] = make_float2(l, w);
        }
      }
#pragma unroll
      for (int ni = 0; ni < 4; ++ni) {
        const int col = n0 + wn + ni * 16 + rc;
#pragma unroll
        for (int r = 0; r < 4; ++r) {
          const int row = m0 + wm + mi * 16 + quad * 4 + r;
          ((__hip_bfloat16*)Cout)[(size_t)row * ldc + col] =
              __float2bfloat16(acc[mi][ni][r]);
        }
      }
    }
  } else {
    const float qsc = (MODE == 1 && aux) ? 1.0f / (8.0f * aux[0]) : 1.0f;
#pragma unroll
    for (int mi = 0; mi < 8; ++mi) {
#pragma unroll
      for (int ni = 0; ni < 4; ++ni) {
        const int col = n0 + wn + ni * 16 + rc;
        const float badd = bias[col];
        if (MODE == 2) {
          const int rowb = m0 + wm + mi * 16 + quad * 4;
          short4v o;
#pragma unroll
          for (int r = 0; r < 4; ++r) o[r] = f2bf_s(acc[mi][ni][r] + badd);
          const size_t idx = (size_t)(rowb >> 11) * (1024u * 2048u) +
                             (size_t)col * 2048u + (size_t)(rowb & 2047);
          *(short4v*)((short*)Cout + idx) = o;
        } else {
#pragma unroll
          for (int r = 0; r < 4; ++r) {
            const int row = m0 + wm + mi * 16 + quad * 4 + r;
            ((__hip_bfloat16*)Cout)[(size_t)row * ldc + col] =
                __float2bfloat16((acc[mi][ni][r] + badd) * qsc);
          }
        }
      }
    }
  }
}

// QKV: grid 384 (32 mtiles x 12 ntiles), chunked XCD swizzle (384 = 8*48).
__global__ __launch_bounds__(512, 2)
void qkv_fused256(const __hip_bfloat16* __restrict__ xb,
                  const __hip_bfloat16* __restrict__ Wt,
                  __hip_bfloat16* __restrict__ qb, __hip_bfloat16* __restrict__ kb,
                  __hip_bfloat16* __restrict__ vt,
                  const float* __restrict__ bq, const float* __restrict__ bk,
                  const float* __restrict__ bv, const float* __restrict__ tptr) {
  extern __shared__ __align__(16) __hip_bfloat16 smem[];
  __hip_bfloat16* sA = smem;
  __hip_bfloat16* sB = smem + 32768;
  const int lin = blockIdx.x;
  const int G  = (lin & 7) * 48 + (lin >> 3);   // bijective: 384 = 8 * 48
  const int mt = G / 12, nt = G % 12;
  const int m0  = mt * 256;
  const int n0g = nt * 256;
  const int z   = n0g >> 10;
  const int n0  = n0g & 1023;
  const __hip_bfloat16* B = Wt + (size_t)z * 1024 * 1024;
  if (z == 0)
    gemm256_body<1>(xb, B, qb, bq, 1024, 1024, 1024, 1024, sA, sB, m0, n0, tptr, nullptr);
  else if (z == 1)
    gemm256_body<1>(xb, B, kb, bk, 1024, 1024, 1024, 1024, sA, sB, m0, n0, nullptr, nullptr);
  else
    gemm256_body<2>(xb, B, vt, bv, 1024, 1024, 1024, 0, sA, sB, m0, n0, nullptr, nullptr);
}

// Scores->P~: grid 256 (4 batches x 8x8 tiles), chunked XCD swizzle (8*32).
__global__ __launch_bounds__(512, 2)
void scores256(const __hip_bfloat16* __restrict__ qb,
               const __hip_bfloat16* __restrict__ kb,
               __hip_bfloat16* __restrict__ Pt,
               float* __restrict__ stats) {
  extern __shared__ __align__(16) __hip_bfloat16 smem[];
  __hip_bfloat16* sA = smem;
  __hip_bfloat16* sB = smem + 32768;
  const int lin = blockIdx.x;
  const int G = (lin & 7) * 32 + (lin >> 3);    // bijective: 256 = 8 * 32
  const int z = G >> 6;
  const int r = G & 63;
  const int y = r >> 3, x = r & 7;
  gemm256_body<3>(qb + (size_t)z * 2048 * 1024, kb + (size_t)z * 2048 * 1024,
                  Pt + (size_t)z * 2048 * 2048, nullptr, 1024, 1024, 1024, 2048,
                  sA, sB, y * 256, x * 256, nullptr, stats + (size_t)z * 2048 * 64);
}

// ---------------------------------------------------------------------------
// PV: proven 128^2 m97-structure path (512 blocks -> 2/CU) + folded stats.
// ---------------------------------------------------------------------------
__device__ __forceinline__
void gemm_pv(const __hip_bfloat16* __restrict__ A,
             const __hip_bfloat16* __restrict__ Bt,
             float* __restrict__ Cout,
             int K, int lda, int ldb, int ldc,
             __hip_bfloat16* __restrict__ sA,
             __hip_bfloat16* __restrict__ sB,
             int m0, int n0,
             const float* __restrict__ aux,   // stats base for batch
             float* __restrict__ Hrow) {
  const int tid  = threadIdx.x;
  const int lane = tid & 63;
  const int wid  = tid >> 6;
  const int wm = (wid >> 1) * 64;
  const int wn = (wid & 1) * 64;
  const int quad = lane >> 4;
  const int rc   = lane & 15;

  f32x4 acc[4][4] = {};

  const int srow = tid >> 3;
  const int scol = ((tid & 7) ^ ((tid >> 3) & 7)) * 8;
  const __hip_bfloat16* Ag = A  + (size_t)(m0 + srow) * lda + scol;
  const __hip_bfloat16* Bg = Bt + (size_t)(n0 + srow) * ldb + scol;

  for (int k0 = 0; k0 < K; k0 += 64) {
#pragma unroll
    for (int p = 0; p < 4; ++p) {
      async_load16(Ag + k0 + (size_t)(32 * p) * lda, &sA[(wid * 64 + 256 * p) * 8]);
      async_load16(Bg + k0 + (size_t)(32 * p) * ldb, &sB[(wid * 64 + 256 * p) * 8]);
    }
    __syncthreads();

#pragma unroll
    for (int kk = 0; kk < 2; ++kk) {
      const int xo = ((kk * 4 + quad) ^ (rc & 7)) * 8;
      short8 af[4], bf[4];
#pragma unroll
      for (int i = 0; i < 4; ++i)
        af[i] = *(const short8*)&sA[(wm + i * 16 + rc) * 64 + xo];
#pragma unroll
      for (int i = 0; i < 4; ++i)
        bf[i] = *(const short8*)&sB[(wn + i * 16 + rc) * 64 + xo];

#pragma unroll
      for (int mi = 0; mi < 4; ++mi)
#pragma unroll
        for (int ni = 0; ni < 4; ++ni)
          acc[mi][ni] = __builtin_amdgcn_mfma_f32_16x16x32_bf16(
              af[mi], bf[ni], acc[mi][ni], 0, 0, 0);
    }
    __syncthreads();
  }

  // Cooperative per-row (l,w) reduction for the block's 128 rows.
  float* lred = (float*)sA;  // 128 floats; LDS free after K-loop barrier
  {
    const int row2 = tid >> 1;               // 0..127 (block-local)
    const float* sp = aux + (size_t)(m0 + row2) * 64 + (tid & 1) * 32;
    float l = 0.f, w = 0.f;
#pragma unroll
    for (int j = 0; j < 8; ++j) {
      const float4 a = *(const float4*)(sp + j * 4);
      l += a.x + a.z;
      w += a.y + a.w;
    }
    l += __shfl_xor(l, 1);
    w += __shfl_xor(w, 1);
    if ((tid & 1) == 0) {
      lred[row2] = 1.0f / l;
      if (Hrow) Hrow[m0 + row2] = __logf(l) - w / l;   // x==0 blocks only
    }
  }
  __syncthreads();
#pragma unroll
  for (int mi = 0; mi < 4; ++mi) {
    float sc[4];
#pragma unroll
    for (int r = 0; r < 4; ++r)
      sc[r] = lred[wm + mi * 16 + quad * 4 + r];
#pragma unroll
    for (int ni = 0; ni < 4; ++ni) {
      const int col = n0 + wn + ni * 16 + rc;
#pragma unroll
      for (int r = 0; r < 4; ++r) {
        const int row = m0 + wm + mi * 16 + quad * 4 + r;
        Cout[(size_t)row * ldc + col] = acc[mi][ni][r] * sc[r];
      }
    }
  }
}

// PV: flat grid 512. Group = 4 blocks (2y x 2x).
__global__ __launch_bounds__(256)
void pv_swz(const __hip_bfloat16* __restrict__ Pt,
            const __hip_bfloat16* __restrict__ vt,
            float* __restrict__ out,
            const float* __restrict__ stats,
            float* __restrict__ Hrow) {
  __shared__ __align__(16) __hip_bfloat16 sA[128 * 64];
  __shared__ __align__(16) __hip_bfloat16 sB[128 * 64];
  const int lin = blockIdx.x;
  const int j = lin & 7, t = lin >> 3;
  const int w = t & 3;
  const int G = j + 8 * (t >> 2);
  const size_t z = G >> 5;
  const int r = G & 31;
  const int y = (r >> 2) * 2 + (w >> 1);
  const int x = (r & 3) * 2 + (w & 1);
  gemm_pv(Pt + z * 2048 * 2048, vt + z * 1024 * 2048,
          out + z * 2048 * 1024, 2048, 2048, 2048, 1024,
          sA, sB, y * 128, x * 128,
          stats + z * 2048 * 64,
          (x == 0) ? (Hrow + z * 2048) : nullptr);
}

// ---------------------------------------------------------------------------
// Fused prep: blocks [0,4096) cast x->xb (bf16x8); blocks [4096,4864) do the
// three weight transposes (z = (b-4096)>>8, 16x16 tiles of 64x64).
__global__ __launch_bounds__(256)
void prep_fused(const float* __restrict__ x, __hip_bfloat16* __restrict__ xb,
                const float* __restrict__ Wq, const float* __restrict__ Wk,
                const float* __restrict__ Wv, __hip_bfloat16* __restrict__ Wt) {
  if (blockIdx.x < 4096) {
    const int i = (blockIdx.x * 256 + threadIdx.x) * 8;
    const float4 a = *(const float4*)(x + i);
    const float4 b = *(const float4*)(x + i + 4);
    short8 o;
    o[0] = f2bf_s(a.x); o[1] = f2bf_s(a.y); o[2] = f2bf_s(a.z); o[3] = f2bf_s(a.w);
    o[4] = f2bf_s(b.x); o[5] = f2bf_s(b.y); o[6] = f2bf_s(b.z); o[7] = f2bf_s(b.w);
    *(short8*)((short*)xb + i) = o;
  } else {
    __shared__ float tile[64][65];
    const int b = blockIdx.x - 4096;
    const int z = b >> 8;
    const int rem = b & 255;
    const int c0 = (rem & 15) * 64;
    const int r0 = (rem >> 4) * 64;
    const float* src = (z == 0) ? Wq : (z == 1) ? Wk : Wv;
    __hip_bfloat16* dst = Wt + (size_t)z * 1024 * 1024;
    const int lane = threadIdx.x & 63;
    const int grp  = threadIdx.x >> 6;
#pragma unroll
    for (int i = 0; i < 16; ++i) {
      const int r = grp * 16 + i;
      tile[r][lane] = src[(size_t)(r0 + r) * 1024 + c0 + lane];
    }
    __syncthreads();
#pragma unroll
    for (int i = 0; i < 16; ++i) {
      const int r = grp * 16 + i;
      dst[(size_t)(c0 + r) * 1024 + r0 + lane] = __float2bfloat16(tile[lane][r]);
    }
  }
}

// One block: sum Hrow[0..8191], out = mean.
__global__ __launch_bounds__(256)
void reduce_entropy(const float* __restrict__ Hrow, float* __restrict__ out) {
  const int tid  = threadIdx.x;
  const int lane = tid & 63;
  const int wid  = tid >> 6;
  float s = 0.f;
#pragma unroll
  for (int j = 0; j < 8; ++j) {
    const float4 a = *(const float4*)(Hrow + j * 1024 + tid * 4);
    s += a.x + a.y + a.z + a.w;
  }
#pragma unroll
  for (int off = 1; off < 64; off <<= 1) s += __shfl_xor(s, off);
  __shared__ float red[4];
  if (lane == 0) red[wid] = s;
  __syncthreads();
  if (tid == 0)
    out[0] = (red[0] + red[1] + red[2] + red[3]) * (1.0f / 8192.0f);
}

// ---------------------------------------------------------------------------
extern "C" void kernel_launch(void* const* d_in, const int* in_sizes, int n_in,
                              void* d_out, int out_size, void* d_ws, size_t ws_size,
                              hipStream_t stream) {
  const float* x    = (const float*)d_in[0];
  const float* Wq   = (const float*)d_in[1];
  const float* bq   = (const float*)d_in[2];
  const float* Wk   = (const float*)d_in[3];
  const float* bk   = (const float*)d_in[4];
  const float* Wv   = (const float*)d_in[5];
  const float* bv   = (const float*)d_in[6];
  const float* temp = (const float*)d_in[7];
  float* out = (float*)d_out;
  char* ws = (char*)d_ws;

  __hip_bfloat16* qb    = (__hip_bfloat16*)(ws + 0);
  __hip_bfloat16* kb    = (__hip_bfloat16*)(ws + 16777216);
  __hip_bfloat16* vt    = (__hip_bfloat16*)(ws + 33554432);
  __hip_bfloat16* xb    = (__hip_bfloat16*)(ws + 50331648);
  __hip_bfloat16* Wt    = (__hip_bfloat16*)(ws + 67108864);
  __hip_bfloat16* Pt    = (__hip_bfloat16*)(ws + 73400320);
  float*          stats = (float*)(ws + 106954752);
  float*          Hrow  = (float*)(ws + 109084672);

  static bool attr_done = false;
  if (!attr_done) {
    hipFuncSetAttribute((const void*)qkv_fused256,
                        hipFuncAttributeMaxDynamicSharedMemorySize, 131072);
    hipFuncSetAttribute((const void*)scores256,
                        hipFuncAttributeMaxDynamicSharedMemorySize, 131072);
    attr_done = true;
  }

  prep_fused<<<4864, 256, 0, stream>>>(x, xb, Wq, Wk, Wv, Wt);

  qkv_fused256<<<384, 512, 131072, stream>>>(xb, Wt, qb, kb, vt, bq, bk, bv, temp);

  scores256<<<256, 512, 131072, stream>>>(qb, kb, Pt, stats);
  pv_swz<<<512, 256, 0, stream>>>(Pt, vt, out, stats, Hrow);

  reduce_entropy<<<1, 256, 0, stream>>>(Hrow, out + 8388608);
}

// Round 8
// 243.246 us; speedup vs baseline: 1.0778x; 1.0778x over previous
//
#include <hip/hip_runtime.h>
#include <hip/hip_bf16.h>
#include <cstdint>
#include <cstddef>

// ThermodynamicAttention: q=xWq+bq, k=xWk+bk, v=xWv+bv (B=4,S=2048,D=1024)
// scores = q@k^T / 8 / temp; probs = softmax(scores); H = mean row entropy
// out0 = probs@v (fp32, 8388608 elems), out1 = H (1 elem)
//
// R16: pipeline lever closed (R9-R15: five 256^2 schedule ports all 77-84us
// vs 69us baseline). New theory from aggregate data: scores/pv stage 512 MB
// through L2/L3 in ~60us ~= 8 TB/s = fabric-bound (qkv is faster only
// because half its staged bytes are L2-hot 6MB weight panels). Lever =
// bigger tile at SAME 2-barrier structure: scores goes 256x128 (512 thr,
// 8 waves 4m x 2n, per-wave code identical to the verified 128^2 body),
// LDS 48KB -> still 2 blocks/CU TLP; staging 512->384 MB (-25%).
// qkv/pv/prep/stats_reduce revert to the round-0 proven forms (250.2us).
//
// Workspace layout (bytes), ~104 MB:
//   0          qb    (bf16, 16MB)  [q pre-scaled by 1/(8*temp)]
//   16777216   kb    (bf16, 16MB)
//   33554432   vt    (bf16 v transposed [b][d][s], 16MB)
//   50331648   xb    (bf16 x, 16MB)
//   67108864   Wt    (bf16 [Wqt|Wkt|Wvt], 6MB)
//   73400320   Pt    (bf16 e^x, 4x2048x2048, 32MB)
//   106954752  stats (fp32 [8192][32][2], 2MB)
//   109051904  inv_l (fp32 [8192], 32KB)
//   109084672  Hrow  (fp32 [8192], 32KB)

typedef __attribute__((ext_vector_type(8))) short short8;
typedef __attribute__((ext_vector_type(4))) short short4v;
typedef __attribute__((ext_vector_type(4))) float f32x4;

#define GLOBAL_AS __attribute__((address_space(1)))
#define LDS_AS __attribute__((address_space(3)))

__device__ __forceinline__ void async_load16(const void* g, void* lds) {
  __builtin_amdgcn_global_load_lds((GLOBAL_AS void*)g, (LDS_AS void*)lds, 16, 0, 0);
}

__device__ __forceinline__ short f2bf_s(float x) {
  __hip_bfloat16 h = __float2bfloat16(x);
  return *reinterpret_cast<short*>(&h);
}

// ---------------------------------------------------------------------------
// bf16 "bt" GEMM body (round-0 verified): C[M,N] = A[M,K] @ Bt[N,K]^T,
// 128x128 tile, BK=64, 256 threads = 4 waves in 2x2, each wave 4x4 grid of
// 16x16x32 MFMA, 2 k-steps. LDS per operand 16KB, XOR-chunk swizzle:
// chunk (row,g) at row*8 + (g ^ (row&7)); staging thread t pass p owns chunk
// t+256p -> source row (t>>3)+32p, col ((t&7)^((t>>3)&7))*8. Read col-group
// kk*4+quad at ((kk*4+quad)^(rc&7)) -> 0 bank conflicts (measured).
// MODE 1: bf16 C + bias, scaled by 1/(8*aux[0]) if aux (q) else 1 (k)
// MODE 2: bf16 transposed-v + bias   (vt[b][col][s], b=row>>11)
// MODE 4: fp32 C scaled by aux[row]  (PV normalization)
// ---------------------------------------------------------------------------
template <int MODE>
__device__ __forceinline__
void gemm_body(const __hip_bfloat16* __restrict__ A,
               const __hip_bfloat16* __restrict__ Bt,
               void* __restrict__ Cout,
               const float* __restrict__ bias,
               int K, int lda, int ldb, int ldc,
               __hip_bfloat16* __restrict__ sA,
               __hip_bfloat16* __restrict__ sB,
               int m0, int n0,
               const float* __restrict__ aux) {
  const int tid  = threadIdx.x;
  const int lane = tid & 63;
  const int wid  = tid >> 6;
  const int wm = (wid >> 1) * 64;
  const int wn = (wid & 1) * 64;
  const int quad = lane >> 4;
  const int rc   = lane & 15;

  f32x4 acc[4][4] = {};

  const int srow = tid >> 3;
  const int scol = ((tid & 7) ^ ((tid >> 3) & 7)) * 8;
  const __hip_bfloat16* Ag = A  + (size_t)(m0 + srow) * lda + scol;
  const __hip_bfloat16* Bg = Bt + (size_t)(n0 + srow) * ldb + scol;

  for (int k0 = 0; k0 < K; k0 += 64) {
#pragma unroll
    for (int p = 0; p < 4; ++p) {
      async_load16(Ag + k0 + (size_t)(32 * p) * lda, &sA[(wid * 64 + 256 * p) * 8]);
      async_load16(Bg + k0 + (size_t)(32 * p) * ldb, &sB[(wid * 64 + 256 * p) * 8]);
    }
    __syncthreads();

#pragma unroll
    for (int kk = 0; kk < 2; ++kk) {
      const int xo = ((kk * 4 + quad) ^ (rc & 7)) * 8;
      short8 af[4], bf[4];
#pragma unroll
      for (int i = 0; i < 4; ++i)
        af[i] = *(const short8*)&sA[(wm + i * 16 + rc) * 64 + xo];
#pragma unroll
      for (int i = 0; i < 4; ++i)
        bf[i] = *(const short8*)&sB[(wn + i * 16 + rc) * 64 + xo];

#pragma unroll
      for (int mi = 0; mi < 4; ++mi)
#pragma unroll
        for (int ni = 0; ni < 4; ++ni)
          acc[mi][ni] = __builtin_amdgcn_mfma_f32_16x16x32_bf16(
              af[mi], bf[ni], acc[mi][ni], 0, 0, 0);
    }
    __syncthreads();
  }

  // Epilogues. C/D layout (m89-verified): row = quad*4 + reg, col = lane&15.
  if (MODE == 4) {
#pragma unroll
    for (int mi = 0; mi < 4; ++mi) {
      float sc[4];
#pragma unroll
      for (int r = 0; r < 4; ++r)
        sc[r] = aux[m0 + wm + mi * 16 + quad * 4 + r];
#pragma unroll
      for (int ni = 0; ni < 4; ++ni) {
        const int col = n0 + wn + ni * 16 + rc;
#pragma unroll
        for (int r = 0; r < 4; ++r) {
          const int row = m0 + wm + mi * 16 + quad * 4 + r;
          ((float*)Cout)[(size_t)row * ldc + col] = acc[mi][ni][r] * sc[r];
        }
      }
    }
  } else {
    const float qsc = (MODE == 1 && aux) ? 1.0f / (8.0f * aux[0]) : 1.0f;
#pragma unroll
    for (int mi = 0; mi < 4; ++mi) {
#pragma unroll
      for (int ni = 0; ni < 4; ++ni) {
        const int col = n0 + wn + ni * 16 + rc;
        const float badd = bias[col];
        if (MODE == 2) {
          const int rowb = m0 + wm + mi * 16 + quad * 4;
          short4v o;
#pragma unroll
          for (int r = 0; r < 4; ++r) o[r] = f2bf_s(acc[mi][ni][r] + badd);
          const size_t idx = (size_t)(rowb >> 11) * (1024u * 2048u) +
                             (size_t)col * 2048u + (size_t)(rowb & 2047);
          *(short4v*)((short*)Cout + idx) = o;
        } else {
#pragma unroll
          for (int r = 0; r < 4; ++r) {
            const int row = m0 + wm + mi * 16 + quad * 4 + r;
            ((__hip_bfloat16*)Cout)[(size_t)row * ldc + col] =
                __float2bfloat16((acc[mi][ni][r] + badd) * qsc);
          }
        }
      }
    }
  }
}

// QKV: flat grid 1536. Group = 8 blocks (fixed y, all 8 x) sharing one A-strip.
__global__ __launch_bounds__(256)
void qkv_fused(const __hip_bfloat16* __restrict__ xb,
               const __hip_bfloat16* __restrict__ Wt,
               __hip_bfloat16* __restrict__ qb, __hip_bfloat16* __restrict__ kb,
               __hip_bfloat16* __restrict__ vt,
               const float* __restrict__ bq, const float* __restrict__ bk,
               const float* __restrict__ bv, const float* __restrict__ tptr) {
  __shared__ __align__(16) __hip_bfloat16 sA[128 * 64];
  __shared__ __align__(16) __hip_bfloat16 sB[128 * 64];
  const int lin = blockIdx.x;
  const int j = lin & 7, t = lin >> 3;
  const int x = t & 7;
  const int G = j + 8 * (t >> 3);
  const int z = G >> 6, y = G & 63;
  const int m0 = y * 128, n0 = x * 128;

  const __hip_bfloat16* B = Wt + (size_t)z * 1024 * 1024;
  if (z == 0)
    gemm_body<1>(xb, B, qb, bq, 1024, 1024, 1024, 1024, sA, sB, m0, n0, tptr);
  else if (z == 1)
    gemm_body<1>(xb, B, kb, bk, 1024, 1024, 1024, 1024, sA, sB, m0, n0, nullptr);
  else
    gemm_body<2>(xb, B, vt, bv, 1024, 1024, 1024, 0, sA, sB, m0, n0, nullptr);
}

// ---------------------------------------------------------------------------
// Scores->P~: 256x128 tile, 512 threads (8 waves, 4m x 2n), BK=64.
// Per-wave fragment/MFMA/swizzle code IDENTICAL to the verified 128^2 body;
// only the staging pass counts (A:4, B:2 over 512 threads), wave mapping
// (wm in {0,64,128,192}, wn in {0,64}) and epilogue bases change.
// Staging per block: A 512KB + B 256KB; grid 512 -> total 384 MB (-25% vs
// the 1024-block 128^2 version). LDS 48KB -> 2 blocks/CU co-resident.
// MODE-3 epilogue: P~ = bf16(e^acc) + per-(row,chunk64) stats (l,w).
// ---------------------------------------------------------------------------
__global__ __launch_bounds__(512)
void scores_bigm(const __hip_bfloat16* __restrict__ qb,
                 const __hip_bfloat16* __restrict__ kb,
                 __hip_bfloat16* __restrict__ Pt,
                 float* __restrict__ stats) {
  __shared__ __align__(16) __hip_bfloat16 sA[256 * 64];  // 32 KB
  __shared__ __align__(16) __hip_bfloat16 sB[128 * 64];  // 16 KB
  const int lin = blockIdx.x;
  const int G = (lin & 7) * 64 + (lin >> 3);   // bijective: 512 = 8 * 64
  const size_t z = G >> 7;                     // batch (128 tiles each)
  const int rr = G & 127;
  const int y = rr >> 4;                       // 0..7  (256-row tiles)
  const int x = rr & 15;                       // 0..15 (128-col tiles)
  const int m0 = y * 256, n0 = x * 128;
  const __hip_bfloat16* A  = qb + z * 2048 * 1024;
  const __hip_bfloat16* Bt = kb + z * 2048 * 1024;
  __hip_bfloat16* Cout = Pt + z * 2048 * 2048;
  float* st = stats + z * 2048 * 64;

  const int tid  = threadIdx.x;
  const int lane = tid & 63;
  const int wid  = tid >> 6;           // 0..7
  const int wm   = (wid >> 1) * 64;    // 0,64,128,192
  const int wn   = (wid & 1) * 64;     // 0,64
  const int quad = lane >> 4;
  const int rc   = lane & 15;

  f32x4 acc[4][4] = {};

  // staging: thread t pass p owns chunk t+512p -> row (t>>3)+64p (low 3 bits
  // of row pass-invariant), pre-swizzled source col ((t&7)^((t>>3)&7))*8.
  const int srow = tid >> 3;                          // 0..63
  const int scol = ((tid & 7) ^ ((tid >> 3) & 7)) * 8;
  const __hip_bfloat16* Ag = A  + (size_t)(m0 + srow) * 1024 + scol;
  const __hip_bfloat16* Bg = Bt + (size_t)(n0 + srow) * 1024 + scol;

  for (int k0 = 0; k0 < 1024; k0 += 64) {
#pragma unroll
    for (int p = 0; p < 4; ++p)
      async_load16(Ag + k0 + (size_t)(64 * p) * 1024, &sA[(tid + 512 * p) * 8]);
#pragma unroll
    for (int p = 0; p < 2; ++p)
      async_load16(Bg + k0 + (size_t)(64 * p) * 1024, &sB[(tid + 512 * p) * 8]);
    __syncthreads();

#pragma unroll
    for (int kk = 0; kk < 2; ++kk) {
      const int xo = ((kk * 4 + quad) ^ (rc & 7)) * 8;
      short8 af[4], bf[4];
#pragma unroll
      for (int i = 0; i < 4; ++i)
        af[i] = *(const short8*)&sA[(wm + i * 16 + rc) * 64 + xo];
#pragma unroll
      for (int i = 0; i < 4; ++i)
        bf[i] = *(const short8*)&sB[(wn + i * 16 + rc) * 64 + xo];

#pragma unroll
      for (int mi = 0; mi < 4; ++mi)
#pragma unroll
        for (int ni = 0; ni < 4; ++ni)
          acc[mi][ni] = __builtin_amdgcn_mfma_f32_16x16x32_bf16(
              af[mi], bf[ni], acc[mi][ni], 0, 0, 0);
    }
    __syncthreads();
  }

  // MODE-3 epilogue (round-0 verified math; bases adapted).
  const int chunk = (n0 + wn) >> 6;
#pragma unroll
  for (int mi = 0; mi < 4; ++mi) {
    float l_acc[4] = {}, w_acc[4] = {};
#pragma unroll
    for (int ni = 0; ni < 4; ++ni)
#pragma unroll
      for (int r = 0; r < 4; ++r) {
        const float xv = acc[mi][ni][r];   // already /(8*temp): q pre-scaled
        const float e = __expf(xv);
        acc[mi][ni][r] = e;
        l_acc[r] += e;
        w_acc[r] += e * xv;
      }
#pragma unroll
    for (int r = 0; r < 4; ++r) {
      float l = l_acc[r], w = w_acc[r];
#pragma unroll
      for (int off = 1; off < 16; off <<= 1) {
        l += __shfl_xor(l, off);
        w += __shfl_xor(w, off);
      }
      if (rc == 0) {
        const int row = m0 + wm + mi * 16 + quad * 4 + r;
        *(float2*)&st[((size_t)row * 32 + chunk) * 2] = make_float2(l, w);
      }
    }
#pragma unroll
    for (int ni = 0; ni < 4; ++ni) {
      const int col = n0 + wn + ni * 16 + rc;
#pragma unroll
      for (int r = 0; r < 4; ++r) {
        const int row = m0 + wm + mi * 16 + quad * 4 + r;
        Cout[(size_t)row * 2048 + col] = __float2bfloat16(acc[mi][ni][r]);
      }
    }
  }
}

// PV: flat grid 512. Group = 4 blocks (2y x 2x). out scaled by inv_l[row].
__global__ __launch_bounds__(256)
void pv_swz(const __hip_bfloat16* __restrict__ Pt,
            const __hip_bfloat16* __restrict__ vt,
            float* __restrict__ out,
            const float* __restrict__ inv_l) {
  __shared__ __align__(16) __hip_bfloat16 sA[128 * 64];
  __shared__ __align__(16) __hip_bfloat16 sB[128 * 64];
  const int lin = blockIdx.x;
  const int j = lin & 7, t = lin >> 3;
  const int w = t & 3;
  const int G = j + 8 * (t >> 2);
  const size_t z = G >> 5;
  const int r = G & 31;
  const int y = (r >> 2) * 2 + (w >> 1);
  const int x = (r & 3) * 2 + (w & 1);
  gemm_body<4>(Pt + z * 2048 * 2048, vt + z * 1024 * 2048,
               out + z * 2048 * 1024, nullptr, 2048, 2048, 2048, 1024,
               sA, sB, y * 128, x * 128, inv_l + z * 2048);
}

// ---------------------------------------------------------------------------
// Fused prep: blocks [0,4096) cast x->xb (bf16x8); blocks [4096,4864) do the
// three weight transposes (z = (b-4096)>>8, 16x16 tiles of 64x64).
__global__ __launch_bounds__(256)
void prep_fused(const float* __restrict__ x, __hip_bfloat16* __restrict__ xb,
                const float* __restrict__ Wq, const float* __restrict__ Wk,
                const float* __restrict__ Wv, __hip_bfloat16* __restrict__ Wt) {
  if (blockIdx.x < 4096) {
    const int i = (blockIdx.x * 256 + threadIdx.x) * 8;
    const float4 a = *(const float4*)(x + i);
    const float4 b = *(const float4*)(x + i + 4);
    short8 o;
    o[0] = f2bf_s(a.x); o[1] = f2bf_s(a.y); o[2] = f2bf_s(a.z); o[3] = f2bf_s(a.w);
    o[4] = f2bf_s(b.x); o[5] = f2bf_s(b.y); o[6] = f2bf_s(b.z); o[7] = f2bf_s(b.w);
    *(short8*)((short*)xb + i) = o;
  } else {
    __shared__ float tile[64][65];
    const int b = blockIdx.x - 4096;
    const int z = b >> 8;
    const int rem = b & 255;
    const int c0 = (rem & 15) * 64;
    const int r0 = (rem >> 4) * 64;
    const float* src = (z == 0) ? Wq : (z == 1) ? Wk : Wv;
    __hip_bfloat16* dst = Wt + (size_t)z * 1024 * 1024;
    const int lane = threadIdx.x & 63;
    const int grp  = threadIdx.x >> 6;
#pragma unroll
    for (int i = 0; i < 16; ++i) {
      const int r = grp * 16 + i;
      tile[r][lane] = src[(size_t)(r0 + r) * 1024 + c0 + lane];
    }
    __syncthreads();
#pragma unroll
    for (int i = 0; i < 16; ++i) {
      const int r = grp * 16 + i;
      dst[(size_t)(c0 + r) * 1024 + r0 + lane] = __float2bfloat16(tile[lane][r]);
    }
  }
}

// ---------------------------------------------------------------------------
// Per-row stats reduction: row's 32 (l,w) chunk-pairs (256B contiguous) ->
// inv_l[row] = 1/sum(l), Hrow[row] = log(l) - w/l. 8192 rows, 32 blocks.
__global__ __launch_bounds__(256)
void stats_reduce(const float* __restrict__ stats,
                  float* __restrict__ inv_l, float* __restrict__ Hrow) {
  const int row = blockIdx.x * 256 + threadIdx.x;
  const float* sp = stats + (size_t)row * 64;
  float l = 0.f, w = 0.f;
#pragma unroll
  for (int j = 0; j < 16; ++j) {
    const float4 a = *(const float4*)(sp + j * 4);
    l += a.x + a.z;
    w += a.y + a.w;
  }
  const float il = 1.0f / l;
  inv_l[row] = il;
  Hrow[row] = __logf(l) - w * il;
}

// One block: sum Hrow[0..8191], out = mean.
__global__ __launch_bounds__(256)
void reduce_entropy(const float* __restrict__ Hrow, float* __restrict__ out) {
  const int tid  = threadIdx.x;
  const int lane = tid & 63;
  const int wid  = tid >> 6;
  float s = 0.f;
#pragma unroll
  for (int j = 0; j < 8; ++j) {
    const float4 a = *(const float4*)(Hrow + j * 1024 + tid * 4);
    s += a.x + a.y + a.z + a.w;
  }
#pragma unroll
  for (int off = 1; off < 64; off <<= 1) s += __shfl_xor(s, off);
  __shared__ float red[4];
  if (lane == 0) red[wid] = s;
  __syncthreads();
  if (tid == 0)
    out[0] = (red[0] + red[1] + red[2] + red[3]) * (1.0f / 8192.0f);
}

// ---------------------------------------------------------------------------
extern "C" void kernel_launch(void* const* d_in, const int* in_sizes, int n_in,
                              void* d_out, int out_size, void* d_ws, size_t ws_size,
                              hipStream_t stream) {
  const float* x    = (const float*)d_in[0];
  const float* Wq   = (const float*)d_in[1];
  const float* bq   = (const float*)d_in[2];
  const float* Wk   = (const float*)d_in[3];
  const float* bk   = (const float*)d_in[4];
  const float* Wv   = (const float*)d_in[5];
  const float* bv   = (const float*)d_in[6];
  const float* temp = (const float*)d_in[7];
  float* out = (float*)d_out;
  char* ws = (char*)d_ws;

  __hip_bfloat16* qb    = (__hip_bfloat16*)(ws + 0);
  __hip_bfloat16* kb    = (__hip_bfloat16*)(ws + 16777216);
  __hip_bfloat16* vt    = (__hip_bfloat16*)(ws + 33554432);
  __hip_bfloat16* xb    = (__hip_bfloat16*)(ws + 50331648);
  __hip_bfloat16* Wt    = (__hip_bfloat16*)(ws + 67108864);
  __hip_bfloat16* Pt    = (__hip_bfloat16*)(ws + 73400320);
  float*          stats = (float*)(ws + 106954752);
  float*          inv_l = (float*)(ws + 109051904);
  float*          Hrow  = (float*)(ws + 109084672);

  prep_fused<<<4864, 256, 0, stream>>>(x, xb, Wq, Wk, Wv, Wt);

  qkv_fused<<<1536, 256, 0, stream>>>(xb, Wt, qb, kb, vt, bq, bk, bv, temp);

  scores_bigm<<<512, 512, 0, stream>>>(qb, kb, Pt, stats);
  stats_reduce<<<32, 256, 0, stream>>>(stats, inv_l, Hrow);
  pv_swz<<<512, 256, 0, stream>>>(Pt, vt, out, inv_l);

  reduce_entropy<<<1, 256, 0, stream>>>(Hrow, out + 8388608);
}